// Round 2
// baseline (1252.015 us; speedup 1.0000x reference)
//
#include <hip/hip_runtime.h>
#include <stddef.h>

#define NN 512
#define CC 128
#define NPOS (NN*NN)

typedef unsigned short u16;
typedef unsigned int   u32;
typedef u16  u16x8  __attribute__((ext_vector_type(8)));
typedef __bf16 bf16x8 __attribute__((ext_vector_type(8)));
typedef float f32x4  __attribute__((ext_vector_type(4)));

__device__ __forceinline__ float b2f(u16 u) {
    union { u32 i; float f; } w; w.i = ((u32)u) << 16; return w.f;
}
__device__ __forceinline__ u16 f2b(float f) {
    union { float f; u32 i; } w; w.f = f;
    u32 r = w.i + 0x7FFFu + ((w.i >> 16) & 1u);
    return (u16)(r >> 16);
}
__device__ __forceinline__ float sigm(float x) { return 1.0f / (1.0f + __expf(-x)); }

struct W6 { const float* p[6]; };   // 0:agw 1:apw 2:bgw 3:bpw 4:gw 5:zw

// ---------------------------------------------------------------------------
// K0: convert the 6 [128x128] f32 weight matrices to bf16 in ws.
// ---------------------------------------------------------------------------
__global__ __launch_bounds__(256) void k0_cvt(W6 w, u16* __restrict__ dst)
{
    const int i = blockIdx.x * 256 + threadIdx.x;     // 6*16384 total
    const int m = i >> 14, r = i & 16383;
    dst[i] = f2b(w.p[m][r]);
}

// ---------------------------------------------------------------------------
// K1: LayerNorm(z) + 4 gated-projection matmuls (a_g,a_p,b_g,b_p) with MFMA.
// Block = 256 threads = 4 waves, 64 positions. a,b written bf16 to ws.
// ---------------------------------------------------------------------------
__global__ __launch_bounds__(256) void k1_ln_proj(
    const float* __restrict__ z,  const float* __restrict__ mask,
    const float* __restrict__ wi, const float* __restrict__ bi,
    const u16* __restrict__ wb,   // bf16 weights (K0 layout)
    const float* __restrict__ agb, const float* __restrict__ apb,
    const float* __restrict__ bgb, const float* __restrict__ bpb,
    u16* __restrict__ a_o, u16* __restrict__ b_o)
{
    __shared__ u16 zn[64][136];   // bf16 normalized z; pitch 136 u16 = 272 B
    const int tid = threadIdx.x;
    const size_t p0 = (size_t)blockIdx.x * 64;

    {   // LayerNorm: 4 threads per position, 32 channels each (f32 loads)
        const int pl = tid >> 2, qt = tid & 3;
        const float* zr = z + (p0 + pl) * CC + qt * 32;
        float v[32];
        #pragma unroll
        for (int h = 0; h < 8; ++h) {
            f32x4 t = *(const f32x4*)(zr + h * 4);
            #pragma unroll
            for (int e = 0; e < 4; ++e) v[h * 4 + e] = t[e];
        }
        float s = 0.f, s2 = 0.f;
        #pragma unroll
        for (int e = 0; e < 32; ++e) { s += v[e]; s2 += v[e] * v[e]; }
        s  += __shfl_xor(s, 1);  s  += __shfl_xor(s, 2);
        s2 += __shfl_xor(s2, 1); s2 += __shfl_xor(s2, 2);
        const float mu   = s * (1.0f / CC);
        const float var  = s2 * (1.0f / CC) - mu * mu;
        const float rstd = rsqrtf(var + 1e-5f);
        #pragma unroll
        for (int e = 0; e < 32; ++e) {
            const int c = qt * 32 + e;
            zn[pl][c] = f2b((v[e] - mu) * rstd * wi[c] + bi[c]);
        }
    }
    __syncthreads();

    const int wave = tid >> 6, lane = tid & 63;
    const int m = lane & 15, q = lane >> 4;

    // A fragments: A[m=lane&15][k=q*8+j], k-block ks -> channels ks*32+q*8..+7
    bf16x8 af[4];
    #pragma unroll
    for (int ks = 0; ks < 4; ++ks)
        af[ks] = *(const bf16x8*)&zn[wave * 16 + m][ks * 32 + q * 8];

    const float* Bv[4] = { agb, apb, bgb, bpb };

    for (int cb = 0; cb < 8; ++cb) {
        const int o = cb * 16 + m;          // out-channel (D col = lane&15)
        f32x4 res[4];
        #pragma unroll
        for (int mt = 0; mt < 4; ++mt) {
            const float bvv = Bv[mt][o];
            f32x4 acc = { bvv, bvv, bvv, bvv };
            const u16* wrow = wb + mt * 16384 + (size_t)o * CC + q * 8;
            #pragma unroll
            for (int ks = 0; ks < 4; ++ks)
                acc = __builtin_amdgcn_mfma_f32_16x16x32_bf16(
                        af[ks], *(const bf16x8*)(wrow + ks * 32), acc, 0, 0, 0);
            res[mt] = acc;
        }
        #pragma unroll
        for (int r = 0; r < 4; ++r) {
            const size_t p = p0 + wave * 16 + q * 4 + r;   // D row = q*4+r
            const float mk = mask[p];
            const size_t idx = p * CC + o;
            a_o[idx] = f2b(mk * sigm(res[0][r]) * res[1][r]);
            b_o[idx] = f2b(mk * sigm(res[2][r]) * res[3][r]);
        }
    }
}

// ---------------------------------------------------------------------------
// K2: x[i,j,c] = sum_k a[i,k,c]*b[j,k,c]  (outgoing). VALU fp32, LDS-staged.
// Block: 32 i x 32 j x 16 channels; thread: 4i x 4j x 4c accumulators.
// Output X written f32 into d_out.
// ---------------------------------------------------------------------------
#define K2_KC 8
#define K2_CP 20

__global__ __launch_bounds__(256) void k2_einsum(
    const u16* __restrict__ A, const u16* __restrict__ B, float* __restrict__ X)
{
    __shared__ float al[K2_KC][32][K2_CP];
    __shared__ float bl[K2_KC][32][K2_CP];
    const int tid = threadIdx.x;
    const int i0 = (blockIdx.x & 15) * 32;
    const int j0 = ((blockIdx.x >> 4) & 15) * 32;
    const int c0 = (blockIdx.x >> 8) * 16;
    const int c4 = tid & 3, jg = (tid >> 2) & 7, ig = tid >> 5;

    const f32x4 zero = { 0.f, 0.f, 0.f, 0.f };
    f32x4 acc[4][4];
    #pragma unroll
    for (int ii = 0; ii < 4; ++ii)
        #pragma unroll
        for (int jj = 0; jj < 4; ++jj) acc[ii][jj] = zero;

    for (int k0 = 0; k0 < NN; k0 += K2_KC) {
        __syncthreads();
        #pragma unroll
        for (int rep = 0; rep < 2; ++rep) {
            const int u = tid + rep * 256;          // 512 16B-chunks each for a,b
            const int h = u & 1, kk = (u >> 1) & 7, ii = u >> 4;
            const size_t rowa = ((size_t)(i0 + ii) * NN + (k0 + kk)) * CC + c0 + h * 8;
            const size_t rowb = ((size_t)(j0 + ii) * NN + (k0 + kk)) * CC + c0 + h * 8;
            u16x8 va = *(const u16x8*)(A + rowa);
            u16x8 vb = *(const u16x8*)(B + rowb);
            #pragma unroll
            for (int e = 0; e < 8; ++e) {
                al[kk][ii][h * 8 + e] = b2f(va[e]);
                bl[kk][ii][h * 8 + e] = b2f(vb[e]);
            }
        }
        __syncthreads();
        #pragma unroll
        for (int kk = 0; kk < K2_KC; ++kk) {
            f32x4 av[4], bv[4];
            #pragma unroll
            for (int t = 0; t < 4; ++t) av[t] = *(const f32x4*)&al[kk][ig * 4 + t][c4 * 4];
            #pragma unroll
            for (int t = 0; t < 4; ++t) bv[t] = *(const f32x4*)&bl[kk][jg * 4 + t][c4 * 4];
            #pragma unroll
            for (int ii = 0; ii < 4; ++ii)
                #pragma unroll
                for (int jj = 0; jj < 4; ++jj)
                    acc[ii][jj] += av[ii] * bv[jj];
        }
    }

    #pragma unroll
    for (int ii = 0; ii < 4; ++ii) {
        const size_t i = i0 + ig * 4 + ii;
        #pragma unroll
        for (int jj = 0; jj < 4; ++jj) {
            const size_t j = j0 + jg * 4 + jj;
            *(f32x4*)(X + (i * NN + j) * CC + c0 + c4 * 4) = acc[ii][jj];
        }
    }
}

// ---------------------------------------------------------------------------
// K3: out = (LayerNorm(x)@z_w^T + z_b) * sigmoid(LayerNorm(z)@g_w^T + g_b)
// In-place on d_out (X). Recomputes LN(z) to avoid storing g in ws.
// ---------------------------------------------------------------------------
__global__ __launch_bounds__(256) void k3_out(
    float* __restrict__ X, const float* __restrict__ z,
    const float* __restrict__ wi, const float* __restrict__ bi,
    const float* __restrict__ wo, const float* __restrict__ bo,
    const u16* __restrict__ wb,   // bf16 weights: [4]=g_w, [5]=z_w
    const float* __restrict__ gbv, const float* __restrict__ zbv)
{
    __shared__ u16 xn[64][136];
    __shared__ u16 zn[64][136];
    const int tid = threadIdx.x;
    const size_t p0 = (size_t)blockIdx.x * 64;

    {
        const int pl = tid >> 2, qt = tid & 3;
        const float* xr = X + (p0 + pl) * CC + qt * 32;
        const float* zr = z + (p0 + pl) * CC + qt * 32;
        float vx[32], vz[32];
        #pragma unroll
        for (int h = 0; h < 8; ++h) {
            f32x4 tx = *(const f32x4*)(xr + h * 4);
            f32x4 tz = *(const f32x4*)(zr + h * 4);
            #pragma unroll
            for (int e = 0; e < 4; ++e) { vx[h * 4 + e] = tx[e]; vz[h * 4 + e] = tz[e]; }
        }
        float sx = 0.f, sx2 = 0.f, sz = 0.f, sz2 = 0.f;
        #pragma unroll
        for (int e = 0; e < 32; ++e) {
            sx += vx[e]; sx2 += vx[e] * vx[e];
            sz += vz[e]; sz2 += vz[e] * vz[e];
        }
        sx  += __shfl_xor(sx, 1);  sx  += __shfl_xor(sx, 2);
        sx2 += __shfl_xor(sx2, 1); sx2 += __shfl_xor(sx2, 2);
        sz  += __shfl_xor(sz, 1);  sz  += __shfl_xor(sz, 2);
        sz2 += __shfl_xor(sz2, 1); sz2 += __shfl_xor(sz2, 2);
        const float mux = sx * (1.0f / CC);
        const float rsx = rsqrtf(sx2 * (1.0f / CC) - mux * mux + 1e-5f);
        const float muz = sz * (1.0f / CC);
        const float rsz = rsqrtf(sz2 * (1.0f / CC) - muz * muz + 1e-5f);
        #pragma unroll
        for (int e = 0; e < 32; ++e) {
            const int c = qt * 32 + e;
            xn[pl][c] = f2b((vx[e] - mux) * rsx * wo[c] + bo[c]);
            zn[pl][c] = f2b((vz[e] - muz) * rsz * wi[c] + bi[c]);
        }
    }
    __syncthreads();

    const int wave = tid >> 6, lane = tid & 63;
    const int m = lane & 15, q = lane >> 4;
    bf16x8 afx[4], afz[4];
    #pragma unroll
    for (int ks = 0; ks < 4; ++ks) {
        afx[ks] = *(const bf16x8*)&xn[wave * 16 + m][ks * 32 + q * 8];
        afz[ks] = *(const bf16x8*)&zn[wave * 16 + m][ks * 32 + q * 8];
    }

    for (int cb = 0; cb < 8; ++cb) {
        const int o = cb * 16 + m;
        const float zb0 = zbv[o], gb0 = gbv[o];
        f32x4 accx = { zb0, zb0, zb0, zb0 };
        f32x4 accg = { gb0, gb0, gb0, gb0 };
        const u16* zwrow = wb + 5 * 16384 + (size_t)o * CC + q * 8;
        const u16* gwrow = wb + 4 * 16384 + (size_t)o * CC + q * 8;
        #pragma unroll
        for (int ks = 0; ks < 4; ++ks) {
            accx = __builtin_amdgcn_mfma_f32_16x16x32_bf16(
                     afx[ks], *(const bf16x8*)(zwrow + ks * 32), accx, 0, 0, 0);
            accg = __builtin_amdgcn_mfma_f32_16x16x32_bf16(
                     afz[ks], *(const bf16x8*)(gwrow + ks * 32), accg, 0, 0, 0);
        }
        #pragma unroll
        for (int r = 0; r < 4; ++r) {
            const size_t p = p0 + wave * 16 + q * 4 + r;
            X[p * CC + o] = accx[r] * sigm(accg[r]);
        }
    }
}

// ---------------------------------------------------------------------------
extern "C" void kernel_launch(void* const* d_in, const int* in_sizes, int n_in,
                              void* d_out, int out_size, void* d_ws, size_t ws_size,
                              hipStream_t stream)
{
    const float* z    = (const float*)d_in[0];
    const float* mask = (const float*)d_in[1];
    const float* wi   = (const float*)d_in[2];
    const float* bi   = (const float*)d_in[3];
    const float* apw  = (const float*)d_in[4];
    const float* apb  = (const float*)d_in[5];
    const float* agw  = (const float*)d_in[6];
    const float* agb  = (const float*)d_in[7];
    const float* bpw  = (const float*)d_in[8];
    const float* bpb  = (const float*)d_in[9];
    const float* bgw  = (const float*)d_in[10];
    const float* bgb  = (const float*)d_in[11];
    const float* gw   = (const float*)d_in[12];
    const float* gb   = (const float*)d_in[13];
    const float* zw   = (const float*)d_in[14];
    const float* zb   = (const float*)d_in[15];
    const float* wo   = (const float*)d_in[16];
    const float* bo   = (const float*)d_in[17];

    u16* a_ws = (u16*)d_ws;                       // 64 MiB bf16
    u16* b_ws = a_ws + (size_t)NPOS * CC;         // 64 MiB bf16
    u16* w_bf = b_ws + (size_t)NPOS * CC;         // 192 KiB bf16 weights
    float* X  = (float*)d_out;                    // x lives in d_out (f32)

    W6 w6; w6.p[0] = agw; w6.p[1] = apw; w6.p[2] = bgw; w6.p[3] = bpw;
    w6.p[4] = gw; w6.p[5] = zw;

    k0_cvt<<<6 * 16384 / 256, 256, 0, stream>>>(w6, w_bf);
    k1_ln_proj<<<NPOS / 64, 256, 0, stream>>>(z, mask, wi, bi, w_bf,
                                              agb, apb, bgb, bpb, a_ws, b_ws);
    k2_einsum<<<16 * 16 * 8, 256, 0, stream>>>(a_ws, b_ws, X);
    k3_out<<<NPOS / 64, 256, 0, stream>>>(X, z, wi, bi, wo, bo, w_bf, gb, zb);
}

// Round 3
// 830.816 us; speedup vs baseline: 1.5070x; 1.5070x over previous
//
#include <hip/hip_runtime.h>
#include <stddef.h>

#define NN 512
#define CC 128
#define NPOS (NN*NN)

typedef unsigned short u16;
typedef unsigned int   u32;
typedef u16  u16x8  __attribute__((ext_vector_type(8)));
typedef __bf16 bf16x8 __attribute__((ext_vector_type(8)));
typedef float f32x4  __attribute__((ext_vector_type(4)));

__device__ __forceinline__ float b2f(u16 u) {
    union { u32 i; float f; } w; w.i = ((u32)u) << 16; return w.f;
}
__device__ __forceinline__ u16 f2b(float f) {
    union { float f; u32 i; } w; w.f = f;
    u32 r = w.i + 0x7FFFu + ((w.i >> 16) & 1u);
    return (u16)(r >> 16);
}
__device__ __forceinline__ float sigm(float x) { return 1.0f / (1.0f + __expf(-x)); }

// async global->LDS 16B copy (LDS dest must be wave-uniform base + lane*16)
__device__ __forceinline__ void gld16(const u16* g, u16* l) {
    __builtin_amdgcn_global_load_lds(
        (const __attribute__((address_space(1))) u32*)g,
        (__attribute__((address_space(3))) u32*)l, 16, 0, 0);
}

struct W6 { const float* p[6]; };   // 0:agw 1:apw 2:bgw 3:bpw 4:gw 5:zw

// ---------------------------------------------------------------------------
// K0: convert the 6 [128x128] f32 weight matrices to bf16 in ws.
// ---------------------------------------------------------------------------
__global__ __launch_bounds__(256) void k0_cvt(W6 w, u16* __restrict__ dst)
{
    const int i = blockIdx.x * 256 + threadIdx.x;     // 6*16384 total
    const int m = i >> 14, r = i & 16383;
    dst[i] = f2b(w.p[m][r]);
}

// ---------------------------------------------------------------------------
// K1: LayerNorm(z) + 4 gated projections (a_g,a_p,b_g,b_p) with MFMA.
// 64 positions/block. Outputs a,b CHANNEL-MAJOR: a_cm[c][p] bf16, via LDS
// staging tile for full-line coalesced global writes.
// ---------------------------------------------------------------------------
__global__ __launch_bounds__(256) void k1_ln_proj(
    const float* __restrict__ z,  const float* __restrict__ mask,
    const float* __restrict__ wi, const float* __restrict__ bi,
    const u16* __restrict__ wb,
    const float* __restrict__ agb, const float* __restrict__ apb,
    const float* __restrict__ bgb, const float* __restrict__ bpb,
    u16* __restrict__ a_cm, u16* __restrict__ b_cm)
{
    __shared__ u16 zn[64][136];    // bf16 normalized z
    __shared__ u16 tile[128][72];  // [c][k-in-block] staging for a then b
    const int tid = threadIdx.x;
    const size_t p0 = (size_t)blockIdx.x * 64;

    {   // LayerNorm: 4 threads/position, 32 channels each
        const int pl = tid >> 2, qt = tid & 3;
        const float* zr = z + (p0 + pl) * CC + qt * 32;
        float v[32];
        #pragma unroll
        for (int h = 0; h < 8; ++h) {
            f32x4 t = *(const f32x4*)(zr + h * 4);
            #pragma unroll
            for (int e = 0; e < 4; ++e) v[h * 4 + e] = t[e];
        }
        float s = 0.f, s2 = 0.f;
        #pragma unroll
        for (int e = 0; e < 32; ++e) { s += v[e]; s2 += v[e] * v[e]; }
        s  += __shfl_xor(s, 1);  s  += __shfl_xor(s, 2);
        s2 += __shfl_xor(s2, 1); s2 += __shfl_xor(s2, 2);
        const float mu   = s * (1.0f / CC);
        const float rstd = rsqrtf(s2 * (1.0f / CC) - mu * mu + 1e-5f);
        #pragma unroll
        for (int e = 0; e < 32; ++e) {
            const int c = qt * 32 + e;
            zn[pl][c] = f2b((v[e] - mu) * rstd * wi[c] + bi[c]);
        }
    }
    __syncthreads();

    const int wave = tid >> 6, lane = tid & 63;
    const int m = lane & 15, q = lane >> 4;
    const int kl = wave * 16 + q * 4;       // + r = position within block

    bf16x8 af[4];
    #pragma unroll
    for (int ks = 0; ks < 4; ++ks)
        af[ks] = *(const bf16x8*)&zn[wave * 16 + m][ks * 32 + q * 8];

    const float* Bv[4] = { agb, apb, bgb, bpb };
    float bstash[8][4];

    for (int cb = 0; cb < 8; ++cb) {
        const int o = cb * 16 + m;
        f32x4 res[4];
        #pragma unroll
        for (int mt = 0; mt < 4; ++mt) {
            const float bvv = Bv[mt][o];
            f32x4 acc = { bvv, bvv, bvv, bvv };
            const u16* wrow = wb + mt * 16384 + (size_t)o * CC + q * 8;
            #pragma unroll
            for (int ks = 0; ks < 4; ++ks)
                acc = __builtin_amdgcn_mfma_f32_16x16x32_bf16(
                        af[ks], *(const bf16x8*)(wrow + ks * 32), acc, 0, 0, 0);
            res[mt] = acc;
        }
        #pragma unroll
        for (int r = 0; r < 4; ++r) {
            const float mk = mask[p0 + kl + r];
            tile[o][kl + r] = f2b(mk * sigm(res[0][r]) * res[1][r]);
            bstash[cb][r]   = mk * sigm(res[2][r]) * res[3][r];
        }
    }
    __syncthreads();
    {   // coalesced channel-major write of a: thread -> one 64B line
        const int c = tid & 127, half = tid >> 7;
        #pragma unroll
        for (int e = 0; e < 4; ++e) {
            u16x8 v = *(const u16x8*)&tile[c][half * 32 + e * 8];
            *(u16x8*)(a_cm + (size_t)c * NPOS + p0 + half * 32 + e * 8) = v;
        }
    }
    __syncthreads();
    for (int cb = 0; cb < 8; ++cb) {
        const int o = cb * 16 + m;
        #pragma unroll
        for (int r = 0; r < 4; ++r) tile[o][kl + r] = f2b(bstash[cb][r]);
    }
    __syncthreads();
    {
        const int c = tid & 127, half = tid >> 7;
        #pragma unroll
        for (int e = 0; e < 4; ++e) {
            u16x8 v = *(const u16x8*)&tile[c][half * 32 + e * 8];
            *(u16x8*)(b_cm + (size_t)c * NPOS + p0 + half * 32 + e * 8) = v;
        }
    }
}

// ---------------------------------------------------------------------------
// K2: per-channel 512x512x512 NT GEMM, MFMA (m97 structure).
// Grid: 128 c x 4 x 4 tiles of 128x128. BK=64 staged as two XOR-swizzled
// BK=32 sub-tiles via global_load_lds width 16. X written bf16 channel-major.
// ---------------------------------------------------------------------------
__global__ __launch_bounds__(256) void k2_gemm(
    const u16* __restrict__ A, const u16* __restrict__ B, u16* __restrict__ X)
{
    __shared__ u16 As[2][128][32];   // [ks-half][row][k] 16 KB
    __shared__ u16 Bs[2][128][32];
    const int tid = threadIdx.x;
    const int bx  = blockIdx.x;
    const int c   = bx >> 4;
    const int i0  = ((bx >> 2) & 3) * 128;
    const int j0  = (bx & 3) * 128;
    const size_t cbase = (size_t)c * NPOS;
    const u16* Ac = A + cbase;
    const u16* Bc = B + cbase;

    const int wave = tid >> 6, lane = tid & 63;
    const int wm = wave >> 1, wn = wave & 1;
    const int m = lane & 15, q = lane >> 4;

    f32x4 acc[4][4];
    const f32x4 zero = { 0.f, 0.f, 0.f, 0.f };
    #pragma unroll
    for (int mt = 0; mt < 4; ++mt)
        #pragma unroll
        for (int nt = 0; nt < 4; ++nt) acc[mt][nt] = zero;

    for (int kt = 0; kt < 8; ++kt) {
        __syncthreads();
        #pragma unroll
        for (int ps = 0; ps < 4; ++ps) {
            const int id   = ps * 256 + tid;       // 1024 16B chunks per matrix
            const int half = id >> 9;
            const int rw   = (id >> 2) & 127;
            const int g    = (id & 3) ^ ((rw >> 1) & 3);   // XOR swizzle
            const size_t goff = (size_t)(kt * 64 + half * 32 + g * 8);
            gld16(Ac + (size_t)(i0 + rw) * NN + goff, &As[0][0][0] + id * 8);
            gld16(Bc + (size_t)(j0 + rw) * NN + goff, &Bs[0][0][0] + id * 8);
        }
        __syncthreads();
        #pragma unroll
        for (int ks = 0; ks < 2; ++ks) {
            bf16x8 af[4], bf[4];
            #pragma unroll
            for (int mt = 0; mt < 4; ++mt) {
                const int row = wm * 64 + mt * 16 + m;
                const int slot = q ^ ((row >> 1) & 3);
                af[mt] = *(const bf16x8*)&As[ks][row][slot * 8];
            }
            #pragma unroll
            for (int nt = 0; nt < 4; ++nt) {
                const int row = wn * 64 + nt * 16 + m;
                const int slot = q ^ ((row >> 1) & 3);
                bf[nt] = *(const bf16x8*)&Bs[ks][row][slot * 8];
            }
            #pragma unroll
            for (int mt = 0; mt < 4; ++mt)
                #pragma unroll
                for (int nt = 0; nt < 4; ++nt)
                    acc[mt][nt] = __builtin_amdgcn_mfma_f32_16x16x32_bf16(
                                    af[mt], bf[nt], acc[mt][nt], 0, 0, 0);
        }
    }

    #pragma unroll
    for (int mt = 0; mt < 4; ++mt) {
        #pragma unroll
        for (int r = 0; r < 4; ++r) {
            const int i = i0 + wm * 64 + mt * 16 + q * 4 + r;
            #pragma unroll
            for (int nt = 0; nt < 4; ++nt) {
                const int j = j0 + wn * 64 + nt * 16 + m;
                X[cbase + (size_t)i * NN + j] = f2b(acc[mt][nt][r]);
            }
        }
    }
}

// ---------------------------------------------------------------------------
// K3: out = (LN(x)@z_w^T + z_b) * sigmoid(LN(z)@g_w^T + g_b).
// Reads x channel-major bf16, writes f32 d_out.
// ---------------------------------------------------------------------------
__global__ __launch_bounds__(256) void k3_out(
    float* __restrict__ out, const u16* __restrict__ x_cm,
    const float* __restrict__ z,
    const float* __restrict__ wi, const float* __restrict__ bi,
    const float* __restrict__ wo, const float* __restrict__ bo,
    const u16* __restrict__ wb,
    const float* __restrict__ gbv, const float* __restrict__ zbv)
{
    __shared__ u16 xn[64][136];
    __shared__ u16 zn[64][136];
    const int tid = threadIdx.x;
    const size_t p0 = (size_t)blockIdx.x * 64;

    {
        const int pl = tid >> 2, qt = tid & 3;
        // ---- x LayerNorm (channel-major reads, coalesced per c-slice) ----
        float vx[32];
        #pragma unroll
        for (int e = 0; e < 32; ++e)
            vx[e] = b2f(x_cm[(size_t)(qt * 32 + e) * NPOS + p0 + pl]);
        float sx = 0.f, sx2 = 0.f;
        #pragma unroll
        for (int e = 0; e < 32; ++e) { sx += vx[e]; sx2 += vx[e] * vx[e]; }
        sx  += __shfl_xor(sx, 1);  sx  += __shfl_xor(sx, 2);
        sx2 += __shfl_xor(sx2, 1); sx2 += __shfl_xor(sx2, 2);
        const float mux = sx * (1.0f / CC);
        const float rsx = rsqrtf(sx2 * (1.0f / CC) - mux * mux + 1e-5f);
        #pragma unroll
        for (int e = 0; e < 32; ++e) {
            const int cc = qt * 32 + e;
            xn[pl][cc] = f2b((vx[e] - mux) * rsx * wo[cc] + bo[cc]);
        }
        // ---- z LayerNorm ----
        const float* zr = z + (p0 + pl) * CC + qt * 32;
        float vz[32];
        #pragma unroll
        for (int h = 0; h < 8; ++h) {
            f32x4 t = *(const f32x4*)(zr + h * 4);
            #pragma unroll
            for (int e = 0; e < 4; ++e) vz[h * 4 + e] = t[e];
        }
        float sz = 0.f, sz2 = 0.f;
        #pragma unroll
        for (int e = 0; e < 32; ++e) { sz += vz[e]; sz2 += vz[e] * vz[e]; }
        sz  += __shfl_xor(sz, 1);  sz  += __shfl_xor(sz, 2);
        sz2 += __shfl_xor(sz2, 1); sz2 += __shfl_xor(sz2, 2);
        const float muz = sz * (1.0f / CC);
        const float rsz = rsqrtf(sz2 * (1.0f / CC) - muz * muz + 1e-5f);
        #pragma unroll
        for (int e = 0; e < 32; ++e) {
            const int cc = qt * 32 + e;
            zn[pl][cc] = f2b((vz[e] - muz) * rsz * wi[cc] + bi[cc]);
        }
    }
    __syncthreads();

    const int wave = tid >> 6, lane = tid & 63;
    const int m = lane & 15, q = lane >> 4;
    bf16x8 afx[4], afz[4];
    #pragma unroll
    for (int ks = 0; ks < 4; ++ks) {
        afx[ks] = *(const bf16x8*)&xn[wave * 16 + m][ks * 32 + q * 8];
        afz[ks] = *(const bf16x8*)&zn[wave * 16 + m][ks * 32 + q * 8];
    }

    for (int cb = 0; cb < 8; ++cb) {
        const int o = cb * 16 + m;
        const float zb0 = zbv[o], gb0 = gbv[o];
        f32x4 accx = { zb0, zb0, zb0, zb0 };
        f32x4 accg = { gb0, gb0, gb0, gb0 };
        const u16* zwrow = wb + 5 * 16384 + (size_t)o * CC + q * 8;
        const u16* gwrow = wb + 4 * 16384 + (size_t)o * CC + q * 8;
        #pragma unroll
        for (int ks = 0; ks < 4; ++ks) {
            accx = __builtin_amdgcn_mfma_f32_16x16x32_bf16(
                     afx[ks], *(const bf16x8*)(zwrow + ks * 32), accx, 0, 0, 0);
            accg = __builtin_amdgcn_mfma_f32_16x16x32_bf16(
                     afz[ks], *(const bf16x8*)(gwrow + ks * 32), accg, 0, 0, 0);
        }
        #pragma unroll
        for (int r = 0; r < 4; ++r) {
            const size_t p = p0 + wave * 16 + q * 4 + r;
            out[p * CC + o] = accx[r] * sigm(accg[r]);
        }
    }
}

// ---------------------------------------------------------------------------
extern "C" void kernel_launch(void* const* d_in, const int* in_sizes, int n_in,
                              void* d_out, int out_size, void* d_ws, size_t ws_size,
                              hipStream_t stream)
{
    const float* z    = (const float*)d_in[0];
    const float* mask = (const float*)d_in[1];
    const float* wi   = (const float*)d_in[2];
    const float* bi   = (const float*)d_in[3];
    const float* apw  = (const float*)d_in[4];
    const float* apb  = (const float*)d_in[5];
    const float* agw  = (const float*)d_in[6];
    const float* agb  = (const float*)d_in[7];
    const float* bpw  = (const float*)d_in[8];
    const float* bpb  = (const float*)d_in[9];
    const float* bgw  = (const float*)d_in[10];
    const float* bgb  = (const float*)d_in[11];
    const float* gw   = (const float*)d_in[12];
    const float* gb   = (const float*)d_in[13];
    const float* zw   = (const float*)d_in[14];
    const float* zb   = (const float*)d_in[15];
    const float* wo   = (const float*)d_in[16];
    const float* bo   = (const float*)d_in[17];

    u16* a_cm = (u16*)d_ws;                         // 64 MiB bf16 [c][p]
    u16* b_cm = a_cm + (size_t)CC * NPOS;           // 64 MiB
    u16* x_cm = b_cm + (size_t)CC * NPOS;           // 64 MiB
    u16* w_bf = x_cm + (size_t)CC * NPOS;           // 192 KiB
    float* out = (float*)d_out;

    W6 w6; w6.p[0] = agw; w6.p[1] = apw; w6.p[2] = bgw; w6.p[3] = bpw;
    w6.p[4] = gw; w6.p[5] = zw;

    k0_cvt<<<6 * 16384 / 256, 256, 0, stream>>>(w6, w_bf);
    k1_ln_proj<<<NPOS / 64, 256, 0, stream>>>(z, mask, wi, bi, w_bf,
                                              agb, apb, bgb, bpb, a_cm, b_cm);
    k2_gemm<<<128 * 16, 256, 0, stream>>>(a_cm, b_cm, x_cm);
    k3_out<<<NPOS / 64, 256, 0, stream>>>(out, x_cm, z, wi, bi, wo, bo,
                                          w_bf, gb, zb);
}

// Round 4
// 493.941 us; speedup vs baseline: 2.5347x; 1.6820x over previous
//
#include <hip/hip_runtime.h>
#include <stddef.h>

#define NN 512
#define CC 128
#define NPOS (NN*NN)

typedef unsigned short u16;
typedef unsigned int   u32;
typedef u16  u16x4  __attribute__((ext_vector_type(4)));
typedef u16  u16x8  __attribute__((ext_vector_type(8)));
typedef __bf16 bf16x8 __attribute__((ext_vector_type(8)));
typedef float f32x4  __attribute__((ext_vector_type(4)));

__device__ __forceinline__ float b2f(u16 u) {
    union { u32 i; float f; } w; w.i = ((u32)u) << 16; return w.f;
}
__device__ __forceinline__ u16 f2b(float f) {
    union { float f; u32 i; } w; w.f = f;
    u32 r = w.i + 0x7FFFu + ((w.i >> 16) & 1u);
    return (u16)(r >> 16);
}
__device__ __forceinline__ float sigm(float x) { return 1.0f / (1.0f + __expf(-x)); }

__device__ __forceinline__ void gld16(const u16* g, u16* l) {
    __builtin_amdgcn_global_load_lds(
        (const __attribute__((address_space(1))) u32*)g,
        (__attribute__((address_space(3))) u32*)l, 16, 0, 0);
}

struct W6 { const float* p[6]; };   // 0:agw 1:apw 2:bgw 3:bpw 4:gw 5:zw

// ---------------------------------------------------------------------------
// K0: pack 6 [128x128] f32 weight matrices into bf16 MFMA-fragment order:
// wpk[mt][cb][ks][lane][8]  (wave B-frag load = contiguous 1 KB)
// lane=(m,q): row = cb*16+m, col = ks*32+q*8+j
// ---------------------------------------------------------------------------
__global__ __launch_bounds__(256) void k0_pack(W6 w, u16* __restrict__ dst)
{
    const int i = blockIdx.x * 256 + threadIdx.x;     // 6*16384 total
    const int mt = i >> 14, r = i & 16383;
    const int cb = r >> 11, ks = (r >> 9) & 3, lane = (r >> 3) & 63, j = r & 7;
    const int row = cb * 16 + (lane & 15);
    const int col = ks * 32 + (lane >> 4) * 8 + j;
    dst[i] = f2b(w.p[mt][row * 128 + col]);
}

// ---------------------------------------------------------------------------
// K1: LayerNorm(z) + 4 gated projections (a_g,a_p,b_g,b_p), MFMA.
// 128 positions/block, 4 waves, 2 m-tiles/wave. Direct channel-major stores.
// ---------------------------------------------------------------------------
__global__ __launch_bounds__(256) void k1_ln_proj(
    const float* __restrict__ z,  const float* __restrict__ mask,
    const float* __restrict__ wi, const float* __restrict__ bi,
    const u16* __restrict__ wpk,
    const float* __restrict__ agb, const float* __restrict__ apb,
    const float* __restrict__ bgb, const float* __restrict__ bpb,
    u16* __restrict__ a_cm, u16* __restrict__ b_cm)
{
    __shared__ u16 zn[128][136];   // bf16 normalized z, pitch 136
    const int tid = threadIdx.x;
    const size_t p0 = (size_t)blockIdx.x * 128;

    {   // LayerNorm: 2 threads/position, 64 channels each
        const int pl = tid >> 1, ht = tid & 1;
        const float* zr = z + (p0 + pl) * CC + ht * 64;
        float v[64];
        #pragma unroll
        for (int h = 0; h < 16; ++h) {
            f32x4 t = *(const f32x4*)(zr + h * 4);
            #pragma unroll
            for (int e = 0; e < 4; ++e) v[h * 4 + e] = t[e];
        }
        float s = 0.f, s2 = 0.f;
        #pragma unroll
        for (int e = 0; e < 64; ++e) { s += v[e]; s2 += v[e] * v[e]; }
        s  += __shfl_xor(s, 1);
        s2 += __shfl_xor(s2, 1);
        const float mu   = s * (1.0f / CC);
        const float rstd = rsqrtf(s2 * (1.0f / CC) - mu * mu + 1e-5f);
        #pragma unroll
        for (int h = 0; h < 8; ++h) {
            u16x8 o8;
            #pragma unroll
            for (int e = 0; e < 8; ++e) {
                const int c = ht * 64 + h * 8 + e;
                o8[e] = f2b((v[h * 8 + e] - mu) * rstd * wi[c] + bi[c]);
            }
            *(u16x8*)&zn[pl][ht * 64 + h * 8] = o8;
        }
    }
    __syncthreads();

    const int wave = tid >> 6, lane = tid & 63;
    const int m = lane & 15, q = lane >> 4;

    bf16x8 af[2][4];
    #pragma unroll
    for (int t = 0; t < 2; ++t)
        #pragma unroll
        for (int ks = 0; ks < 4; ++ks)
            af[t][ks] = *(const bf16x8*)&zn[wave * 32 + t * 16 + m][ks * 32 + q * 8];

    f32x4 mkv[2];
    #pragma unroll
    for (int t = 0; t < 2; ++t)
        mkv[t] = *(const f32x4*)(mask + p0 + wave * 32 + t * 16 + q * 4);

    const float* Bv[4] = { agb, apb, bgb, bpb };

    for (int cb = 0; cb < 8; ++cb) {
        const int o = cb * 16 + m;
        f32x4 res[4][2];
        #pragma unroll
        for (int mt = 0; mt < 4; ++mt) {
            const float bvv = Bv[mt][o];
            #pragma unroll
            for (int t = 0; t < 2; ++t) res[mt][t] = f32x4{ bvv, bvv, bvv, bvv };
            const u16* wp = wpk + ((size_t)((mt * 8 + cb) * 4)) * 512 + (size_t)lane * 8;
            bf16x8 wf[4];
            #pragma unroll
            for (int ks = 0; ks < 4; ++ks) wf[ks] = *(const bf16x8*)(wp + ks * 512);
            #pragma unroll
            for (int ks = 0; ks < 4; ++ks)
                #pragma unroll
                for (int t = 0; t < 2; ++t)
                    res[mt][t] = __builtin_amdgcn_mfma_f32_16x16x32_bf16(
                                   af[t][ks], wf[ks], res[mt][t], 0, 0, 0);
        }
        #pragma unroll
        for (int t = 0; t < 2; ++t) {
            u16x4 av, bv;
            #pragma unroll
            for (int r = 0; r < 4; ++r) {
                const float mk = mkv[t][r];
                av[r] = f2b(mk * sigm(res[0][t][r]) * res[1][t][r]);
                bv[r] = f2b(mk * sigm(res[2][t][r]) * res[3][t][r]);
            }
            const size_t off = (size_t)o * NPOS + p0 + wave * 32 + t * 16 + q * 4;
            *(u16x4*)(a_cm + off) = av;
            *(u16x4*)(b_cm + off) = bv;
        }
    }
}

// ---------------------------------------------------------------------------
// K2: per-channel 512x512x512 NT GEMM, MFMA (m97 structure). Unchanged.
// ---------------------------------------------------------------------------
__global__ __launch_bounds__(256) void k2_gemm(
    const u16* __restrict__ A, const u16* __restrict__ B, u16* __restrict__ X)
{
    __shared__ u16 As[2][128][32];
    __shared__ u16 Bs[2][128][32];
    const int tid = threadIdx.x;
    const int bx  = blockIdx.x;
    const int c   = bx >> 4;
    const int i0  = ((bx >> 2) & 3) * 128;
    const int j0  = (bx & 3) * 128;
    const size_t cbase = (size_t)c * NPOS;
    const u16* Ac = A + cbase;
    const u16* Bc = B + cbase;

    const int wave = tid >> 6, lane = tid & 63;
    const int wm = wave >> 1, wn = wave & 1;
    const int m = lane & 15, q = lane >> 4;

    f32x4 acc[4][4];
    const f32x4 zero = { 0.f, 0.f, 0.f, 0.f };
    #pragma unroll
    for (int mt = 0; mt < 4; ++mt)
        #pragma unroll
        for (int nt = 0; nt < 4; ++nt) acc[mt][nt] = zero;

    for (int kt = 0; kt < 8; ++kt) {
        __syncthreads();
        #pragma unroll
        for (int ps = 0; ps < 4; ++ps) {
            const int id   = ps * 256 + tid;
            const int half = id >> 9;
            const int rw   = (id >> 2) & 127;
            const int g    = (id & 3) ^ ((rw >> 1) & 3);
            const size_t goff = (size_t)(kt * 64 + half * 32 + g * 8);
            gld16(Ac + (size_t)(i0 + rw) * NN + goff, &As[0][0][0] + id * 8);
            gld16(Bc + (size_t)(j0 + rw) * NN + goff, &Bs[0][0][0] + id * 8);
        }
        __syncthreads();
        #pragma unroll
        for (int ks = 0; ks < 2; ++ks) {
            bf16x8 af[4], bf[4];
            #pragma unroll
            for (int mt = 0; mt < 4; ++mt) {
                const int row = wm * 64 + mt * 16 + m;
                const int slot = q ^ ((row >> 1) & 3);
                af[mt] = *(const bf16x8*)&As[ks][row][slot * 8];
            }
            #pragma unroll
            for (int nt = 0; nt < 4; ++nt) {
                const int row = wn * 64 + nt * 16 + m;
                const int slot = q ^ ((row >> 1) & 3);
                bf[nt] = *(const bf16x8*)&Bs[ks][row][slot * 8];
            }
            #pragma unroll
            for (int mt = 0; mt < 4; ++mt)
                #pragma unroll
                for (int nt = 0; nt < 4; ++nt)
                    acc[mt][nt] = __builtin_amdgcn_mfma_f32_16x16x32_bf16(
                                    af[mt], bf[nt], acc[mt][nt], 0, 0, 0);
        }
    }

    #pragma unroll
    for (int mt = 0; mt < 4; ++mt) {
        #pragma unroll
        for (int r = 0; r < 4; ++r) {
            const int i = i0 + wm * 64 + mt * 16 + q * 4 + r;
            #pragma unroll
            for (int nt = 0; nt < 4; ++nt) {
                const int j = j0 + wn * 64 + nt * 16 + m;
                X[cbase + (size_t)i * NN + j] = f2b(acc[mt][nt][r]);
            }
        }
    }
}

// ---------------------------------------------------------------------------
// K3: out = (LN(x)@z_w^T + z_b) * sigmoid(LN(z)@g_w^T + g_b)
// 128 positions/block. x read via coalesced LDS transpose; packed weights.
// ---------------------------------------------------------------------------
__global__ __launch_bounds__(256) void k3_out(
    float* __restrict__ out, const u16* __restrict__ x_cm,
    const float* __restrict__ z,
    const float* __restrict__ wi, const float* __restrict__ bi,
    const float* __restrict__ wo, const float* __restrict__ bo,
    const u16* __restrict__ wpk,
    const float* __restrict__ gbv, const float* __restrict__ zbv)
{
    __shared__ u16 A[128][136];    // zn, later xn
    __shared__ u16 Bt[128][136];   // x tile, channel-major [c][p]
    const int tid = threadIdx.x;
    const size_t p0 = (size_t)blockIdx.x * 128;
    const int wave = tid >> 6, lane = tid & 63;
    const int m = lane & 15, q = lane >> 4;
    const int pl = tid >> 1, ht = tid & 1;

    {   // ---- z LayerNorm -> A ----
        const float* zr = z + (p0 + pl) * CC + ht * 64;
        float v[64];
        #pragma unroll
        for (int h = 0; h < 16; ++h) {
            f32x4 t = *(const f32x4*)(zr + h * 4);
            #pragma unroll
            for (int e = 0; e < 4; ++e) v[h * 4 + e] = t[e];
        }
        float s = 0.f, s2 = 0.f;
        #pragma unroll
        for (int e = 0; e < 64; ++e) { s += v[e]; s2 += v[e] * v[e]; }
        s  += __shfl_xor(s, 1);
        s2 += __shfl_xor(s2, 1);
        const float mu   = s * (1.0f / CC);
        const float rstd = rsqrtf(s2 * (1.0f / CC) - mu * mu + 1e-5f);
        #pragma unroll
        for (int h = 0; h < 8; ++h) {
            u16x8 o8;
            #pragma unroll
            for (int e = 0; e < 8; ++e) {
                const int c = ht * 64 + h * 8 + e;
                o8[e] = f2b((v[h * 8 + e] - mu) * rstd * wi[c] + bi[c]);
            }
            *(u16x8*)&A[pl][ht * 64 + h * 8] = o8;
        }
    }
    // ---- load x tile channel-major (coalesced) -> Bt ----
    {
        const int c = tid >> 1, seg = tid & 1;
        #pragma unroll
        for (int e = 0; e < 8; ++e) {
            u16x8 vv = *(const u16x8*)(x_cm + (size_t)c * NPOS + p0 + seg * 64 + e * 8);
            *(u16x8*)&Bt[c][seg * 64 + e * 8] = vv;
        }
    }
    __syncthreads();

    bf16x8 afz[2][4];
    #pragma unroll
    for (int t = 0; t < 2; ++t)
        #pragma unroll
        for (int ks = 0; ks < 4; ++ks)
            afz[t][ks] = *(const bf16x8*)&A[wave * 32 + t * 16 + m][ks * 32 + q * 8];
    __syncthreads();

    {   // ---- x LayerNorm: read Bt columns, write xn into A ----
        float v[64];
        #pragma unroll
        for (int e = 0; e < 64; ++e) v[e] = b2f(Bt[ht * 64 + e][pl]);
        float s = 0.f, s2 = 0.f;
        #pragma unroll
        for (int e = 0; e < 64; ++e) { s += v[e]; s2 += v[e] * v[e]; }
        s  += __shfl_xor(s, 1);
        s2 += __shfl_xor(s2, 1);
        const float mu   = s * (1.0f / CC);
        const float rstd = rsqrtf(s2 * (1.0f / CC) - mu * mu + 1e-5f);
        #pragma unroll
        for (int h = 0; h < 8; ++h) {
            u16x8 o8;
            #pragma unroll
            for (int e = 0; e < 8; ++e) {
                const int c = ht * 64 + h * 8 + e;
                o8[e] = f2b((v[h * 8 + e] - mu) * rstd * wo[c] + bo[c]);
            }
            *(u16x8*)&A[pl][ht * 64 + h * 8] = o8;
        }
    }
    __syncthreads();

    bf16x8 afx[2][4];
    #pragma unroll
    for (int t = 0; t < 2; ++t)
        #pragma unroll
        for (int ks = 0; ks < 4; ++ks)
            afx[t][ks] = *(const bf16x8*)&A[wave * 32 + t * 16 + m][ks * 32 + q * 8];

    for (int cb = 0; cb < 8; ++cb) {
        const int o = cb * 16 + m;
        const float gb0 = gbv[o], zb0 = zbv[o];
        f32x4 accg[2], accx[2];
        #pragma unroll
        for (int t = 0; t < 2; ++t) {
            accg[t] = f32x4{ gb0, gb0, gb0, gb0 };
            accx[t] = f32x4{ zb0, zb0, zb0, zb0 };
        }
        const u16* wpg = wpk + ((size_t)((4 * 8 + cb) * 4)) * 512 + (size_t)lane * 8;
        const u16* wpz = wpk + ((size_t)((5 * 8 + cb) * 4)) * 512 + (size_t)lane * 8;
        bf16x8 wg[4], wz[4];
        #pragma unroll
        for (int ks = 0; ks < 4; ++ks) {
            wg[ks] = *(const bf16x8*)(wpg + ks * 512);
            wz[ks] = *(const bf16x8*)(wpz + ks * 512);
        }
        #pragma unroll
        for (int ks = 0; ks < 4; ++ks)
            #pragma unroll
            for (int t = 0; t < 2; ++t) {
                accg[t] = __builtin_amdgcn_mfma_f32_16x16x32_bf16(
                            afz[t][ks], wg[ks], accg[t], 0, 0, 0);
                accx[t] = __builtin_amdgcn_mfma_f32_16x16x32_bf16(
                            afx[t][ks], wz[ks], accx[t], 0, 0, 0);
            }
        #pragma unroll
        for (int t = 0; t < 2; ++t)
            #pragma unroll
            for (int r = 0; r < 4; ++r) {
                const size_t p = p0 + wave * 32 + t * 16 + q * 4 + r;
                out[p * CC + o] = accx[t][r] * sigm(accg[t][r]);
            }
    }
}

// ---------------------------------------------------------------------------
extern "C" void kernel_launch(void* const* d_in, const int* in_sizes, int n_in,
                              void* d_out, int out_size, void* d_ws, size_t ws_size,
                              hipStream_t stream)
{
    const float* z    = (const float*)d_in[0];
    const float* mask = (const float*)d_in[1];
    const float* wi   = (const float*)d_in[2];
    const float* bi   = (const float*)d_in[3];
    const float* apw  = (const float*)d_in[4];
    const float* apb  = (const float*)d_in[5];
    const float* agw  = (const float*)d_in[6];
    const float* agb  = (const float*)d_in[7];
    const float* bpw  = (const float*)d_in[8];
    const float* bpb  = (const float*)d_in[9];
    const float* bgw  = (const float*)d_in[10];
    const float* bgb  = (const float*)d_in[11];
    const float* gw   = (const float*)d_in[12];
    const float* gb   = (const float*)d_in[13];
    const float* zw   = (const float*)d_in[14];
    const float* zb   = (const float*)d_in[15];
    const float* wo   = (const float*)d_in[16];
    const float* bo   = (const float*)d_in[17];

    u16* a_cm = (u16*)d_ws;                         // 64 MiB bf16 [c][p]
    u16* b_cm = a_cm + (size_t)CC * NPOS;           // 64 MiB
    u16* x_cm = b_cm + (size_t)CC * NPOS;           // 64 MiB
    u16* w_pk = x_cm + (size_t)CC * NPOS;           // 192 KiB packed frags
    float* out = (float*)d_out;

    W6 w6; w6.p[0] = agw; w6.p[1] = apw; w6.p[2] = bgw; w6.p[3] = bpw;
    w6.p[4] = gw; w6.p[5] = zw;

    k0_pack<<<6 * 16384 / 256, 256, 0, stream>>>(w6, w_pk);
    k1_ln_proj<<<NPOS / 128, 256, 0, stream>>>(z, mask, wi, bi, w_pk,
                                               agb, apb, bgb, bpb, a_cm, b_cm);
    k2_gemm<<<128 * 16, 256, 0, stream>>>(a_cm, b_cm, x_cm);
    k3_out<<<NPOS / 128, 256, 0, stream>>>(out, x_cm, z, wi, bi, wo, bo,
                                           w_pk, gb, zb);
}